// Round 13
// baseline (460.064 us; speedup 1.0000x reference)
//
#include <hip/hip_runtime.h>
#include <hip/hip_fp16.h>
#include <math.h>

#define FDIM 64
#define CATDIM 192
#define CH 2048      // edges per chunk in the binning passes (high occupancy)
#define MAXNB 1024   // max dest buckets (N<65536)
#define SCTILE 2048  // elements per block in the bh scan (nblkS <= 256)

// ============ pass H: per-chunk LDS histogram over dest buckets ============
// writes BUCKET-MAJOR bh[g][b][c]; scattered 4B writes are L2-resident (bh ~3.5MB)

__global__ __launch_bounds__(256) void k_chist(const int* __restrict__ ei0,
                                               const int* __restrict__ ei1,
                                               const int* __restrict__ ei2,
                                               int* __restrict__ bh,   // [3][NB][nchunks]
                                               int NB, int nchunks, int E) {
    __shared__ int hist[MAXNB];
    const int c = blockIdx.x, g = blockIdx.y, tid = threadIdx.x;
    const int* dest = (g == 0 ? ei0 : g == 1 ? ei1 : ei2) + E;

    for (int i = tid; i < NB; i += 256) hist[i] = 0;
    __syncthreads();

    const int lo = c * CH, hi = min(E, lo + CH);
    for (int i = lo + tid; i < hi; i += 256) atomicAdd(&hist[dest[i] >> 6], 1);
    __syncthreads();

    for (int i = tid; i < NB; i += 256)
        bh[((size_t)g * NB + i) * nchunks + c] = hist[i];
}

// ============ 3-phase parallel exclusive scan of bh (bucket-major) per graph ============

__global__ __launch_bounds__(256) void k_scan_a(const int* __restrict__ bh,
                                                int* __restrict__ bsum,   // [3][nblkS]
                                                int L, int nblkS) {
    __shared__ int s[256];
    const int b = blockIdx.x, g = blockIdx.y, tid = threadIdx.x;
    const int* data = bh + (size_t)g * L;
    const int base = b * SCTILE + tid * 8;
    int v = 0;
#pragma unroll
    for (int j = 0; j < 8; ++j) {
        int idx = base + j;
        if (idx < L) v += data[idx];
    }
    s[tid] = v;
    __syncthreads();
    for (int d = 128; d > 0; d >>= 1) {
        if (tid < d) s[tid] += s[tid + d];
        __syncthreads();
    }
    if (tid == 0) bsum[g * nblkS + b] = s[0];
}

__global__ __launch_bounds__(256) void k_scan_b(int* __restrict__ bsum, int nblkS) {
    __shared__ int s[256];
    const int g = blockIdx.x, tid = threadIdx.x;
    int v = (tid < nblkS) ? bsum[g * nblkS + tid] : 0;
    s[tid] = v;
    __syncthreads();
    for (int d = 1; d < 256; d <<= 1) {
        int t = (tid >= d) ? s[tid - d] : 0;
        __syncthreads();
        s[tid] += t;
        __syncthreads();
    }
    if (tid < nblkS) bsum[g * nblkS + tid] = s[tid] - v;   // exclusive
}

// scan_c also emits bucket bases: element idx%nchunks==0 is bucket idx/nchunks's
// first chunk -> its exclusive prefix = bucket base.

__global__ __launch_bounds__(256) void k_scan_c(int* __restrict__ bh,
                                                const int* __restrict__ bsum,
                                                int* __restrict__ bbase,   // [3][NB+1]
                                                int L, int nblkS,
                                                int NB, int nchunks, int E) {
    __shared__ int s[256];
    const int b = blockIdx.x, g = blockIdx.y, tid = threadIdx.x;
    int* data = bh + (size_t)g * L;
    const int base = b * SCTILE + tid * 8;

    int e[8];
    int tot = 0;
#pragma unroll
    for (int j = 0; j < 8; ++j) {
        e[j] = (base + j < L) ? data[base + j] : 0;
        tot += e[j];
    }
    s[tid] = tot;
    __syncthreads();
    for (int d = 1; d < 256; d <<= 1) {
        int t = (tid >= d) ? s[tid - d] : 0;
        __syncthreads();
        s[tid] += t;
        __syncthreads();
    }
    int run = bsum[g * nblkS + b] + s[tid] - tot;
#pragma unroll
    for (int j = 0; j < 8; ++j) {
        int idx = base + j;
        if (idx < L) {
            int v = e[j];
            data[idx] = run;
            if (idx % nchunks == 0) bbase[g * (NB + 1) + idx / nchunks] = run;
            run += v;
        }
    }
    if (b == 0 && tid == 0) bbase[g * (NB + 1) + NB] = E;
}

// ============ pass F: deterministic binned scatter (LDS cursors only) ============

__global__ __launch_bounds__(256) void k_cfill(const int* __restrict__ ei0,
                                               const int* __restrict__ ei1,
                                               const int* __restrict__ ei2,
                                               const float* __restrict__ w1,
                                               const float* __restrict__ w2,
                                               const int* __restrict__ bhs,  // [3][NB][nchunks] scanned
                                               int2* __restrict__ barr,      // [3][E]
                                               int NB, int nchunks, int E) {
    __shared__ int cur[MAXNB];
    const int c = blockIdx.x, g = blockIdx.y, tid = threadIdx.x;
    const int* e = (g == 0 ? ei0 : g == 1 ? ei1 : ei2);
    const float* w = (g == 1 ? w1 : w2);
    const int* srcp = e;
    const int* dest = e + E;
    int2* bout = barr + (size_t)g * E;

    for (int i = tid; i < NB; i += 256)
        cur[i] = bhs[((size_t)g * NB + i) * nchunks + c];
    __syncthreads();

    const int lo = c * CH, hi = min(E, lo + CH);
    for (int i = lo + tid; i < hi; i += 256) {
        int d = dest[i];
        int slot = atomicAdd(&cur[d >> 6], 1);
        float wv = (g == 0) ? 0.f : w[i];
        bout[slot] = make_int2(srcp[i] | ((d & 63) << 16), __float_as_int(wv));
    }
}

// ============ pass D: per-bucket degree/dis + rowptr ============

__global__ __launch_bounds__(256) void k_deg(const int2* __restrict__ barr,  // [3][E]
                                             const int* __restrict__ bbase,  // [3][NB+1]
                                             int* __restrict__ rowptr,       // [3][N+1]
                                             float* __restrict__ dis,        // [3][N]
                                             int N, int E, int NB) {
    __shared__ int hist[64];
    __shared__ float wsum[64];
    __shared__ int sc[64];

    const int b = blockIdx.x, g = blockIdx.y, tid = threadIdx.x;
    const int2* bin = barr + (size_t)g * E;
    const int beg = bbase[g * (NB + 1) + b];
    const int end = bbase[g * (NB + 1) + b + 1];

    if (tid < 64) { hist[tid] = 0; wsum[tid] = 1.0f; }   // 1.0 = self-loop weight
    __syncthreads();

    for (int t = beg + tid; t < end; t += 256) {
        int2 p = bin[t];
        int dl = (p.x >> 16) & 63;
        atomicAdd(&hist[dl], 1);
        if (g) atomicAdd(&wsum[dl], __int_as_float(p.y));
    }
    __syncthreads();

    if (tid < 64) sc[tid] = hist[tid];
    __syncthreads();
    for (int d = 1; d < 64; d <<= 1) {
        int t = 0;
        if (tid < 64 && tid >= d) t = sc[tid - d];
        __syncthreads();
        if (tid < 64) sc[tid] += t;
        __syncthreads();
    }
    if (tid < 64) {
        int node = b * 64 + tid;
        if (node < N) {
            rowptr[g * (N + 1) + node] = beg + (sc[tid] - hist[tid]);
            float s = g ? wsum[tid] : (1.0f + (float)hist[tid]);
            dis[g * N + node] = rsqrtf(s);
        }
    }
    if (b == NB - 1 && tid == 0) rowptr[g * (N + 1) + N] = end;
}

// ============ pass P: placement with fused val = w * dis[src] (fp16 packed) ============

__global__ __launch_bounds__(256) void k_place(const int2* __restrict__ barr,  // [3][E]
                                               const int* __restrict__ bbase,  // [3][NB+1]
                                               const int* __restrict__ rowptr, // [3][N+1]
                                               const float* __restrict__ dis,  // [3][N]
                                               unsigned* __restrict__ csr,     // [3][E]
                                               int N, int E, int NB) {
    __shared__ int cur[64];
    const int b = blockIdx.x, g = blockIdx.y, tid = threadIdx.x;
    const int2* bin = barr + (size_t)g * E;
    const int beg = bbase[g * (NB + 1) + b];
    const int end = bbase[g * (NB + 1) + b + 1];

    if (tid < 64) {
        int node = b * 64 + tid;
        cur[tid] = (node < N) ? rowptr[g * (N + 1) + node] - beg : 0;
    }
    __syncthreads();

    for (int t = beg + tid; t < end; t += 256) {
        int2 p = bin[t];
        int dl = (p.x >> 16) & 63;
        int pos = atomicAdd(&cur[dl], 1);
        int src = p.x & 0xFFFF;
        float wv = g ? __int_as_float(p.y) : 1.0f;
        float v = wv * dis[g * N + src];
        unsigned short wb = __half_as_ushort(__float2half(v));
        csr[(size_t)g * E + beg + pos] = (unsigned)src | ((unsigned)wb << 16);
    }
}

// ============ GEMM: out = A * W^T, fp16 output in SPLIT layout [2][N][32] ============
// (feature halves separated so each gather half-dispatch touches 3.2MB of h)

template <typename T> __device__ inline float4 load4f(const T* p);
template <> __device__ inline float4 load4f<float>(const float* p) {
    return *reinterpret_cast<const float4*>(p);
}
template <> __device__ inline float4 load4f<__half>(const __half* p) {
    __half2 a = *reinterpret_cast<const __half2*>(p);
    __half2 b = *reinterpret_cast<const __half2*>(p + 2);
    float2 fa = __half22float2(a), fb = __half22float2(b);
    return make_float4(fa.x, fa.y, fb.x, fb.y);
}

template <int K, int KCH, typename TA>
__global__ __launch_bounds__(256) void k_gemm(const TA* __restrict__ A,
                                              const float* __restrict__ W,
                                              __half* __restrict__ out, int n) {
    __shared__ float wt[KCH * 65];
    __shared__ float xs[64 * 36];

    const int tid = threadIdx.x;
    const int n0 = blockIdx.x * 64;

    const int f = tid & 63;
    const int q = tid >> 6;
    float acc[16];
#pragma unroll
    for (int j = 0; j < 16; ++j) acc[j] = 0.f;

    for (int kc = 0; kc < K; kc += 32) {
        __syncthreads();
        if ((kc % KCH) == 0) {
            for (int idx = tid; idx < FDIM * KCH; idx += 256) {
                int fr = idx / KCH;
                int kr = idx - fr * KCH;
                wt[kr * 65 + fr] = W[fr * K + kc + kr];
            }
        }
#pragma unroll
        for (int u = tid; u < 512; u += 256) {
            int node = u >> 3;
            int k4 = u & 7;
            int gn = n0 + node;
            float4 a = make_float4(0.f, 0.f, 0.f, 0.f);
            if (gn < n) a = load4f(&A[(size_t)gn * K + kc + k4 * 4]);
            *reinterpret_cast<float4*>(&xs[node * 36 + k4 * 4]) = a;
        }
        __syncthreads();

        const int kb = kc % KCH;
#pragma unroll
        for (int kk = 0; kk < 32; kk += 4) {
            float w0 = wt[(kb + kk + 0) * 65 + f];
            float w1 = wt[(kb + kk + 1) * 65 + f];
            float w2 = wt[(kb + kk + 2) * 65 + f];
            float w3 = wt[(kb + kk + 3) * 65 + f];
#pragma unroll
            for (int jj = 0; jj < 16; ++jj) {
                int j = jj * 4 + q;
                float4 av = *reinterpret_cast<const float4*>(&xs[j * 36 + kk]);
                acc[jj] = fmaf(av.x, w0, fmaf(av.y, w1, fmaf(av.z, w2, fmaf(av.w, w3, acc[jj]))));
            }
        }
    }

    const int p = f >> 5, fl = f & 31;
#pragma unroll
    for (int jj = 0; jj < 16; ++jj) {
        int node = n0 + jj * 4 + q;
        if (node < n)
            out[((size_t)p * n + node) * 32 + fl] = __float2half(acc[jj]);
    }
}

// ============ dgconv gather (feature half P) x3 graphs + self-loop + bias + relu ============
// wave = node; lane = (eq = lane>>4 edge slot, fpair = lane&15 feature pair of half P).
// CSR entries via wave-uniform s_loads; per-lane 3 cndmask select among 4 edges
// (loop-invariant masks); one 4B half2 load per lane per quad -> 64B/row, 1 txn.
// 2 quads in flight = 8 rows/wave. h half working set 3.2MB < 4MB/XCD L2.

template <int P>
__global__ __launch_bounds__(256) void k_gather(const __half* __restrict__ hh,   // [2][N][32]
                                                const float* __restrict__ dis,   // [3][N]
                                                const int* __restrict__ rowptr,  // [3][N+1]
                                                const unsigned* __restrict__ csr,// [3][E]
                                                const float* __restrict__ bias,  // [64]
                                                __half* __restrict__ cat,        // [N][192]
                                                int N, int E) {
    const int i = blockIdx.x * 4 + (threadIdx.x >> 6);
    if (i >= N) return;
    const int lane = threadIdx.x & 63;
    const int fpair = lane & 15;
    const bool e0 = (lane & 16) != 0;
    const bool e1 = (lane & 32) != 0;

    const __half2* h2 = reinterpret_cast<const __half2*>(hh) + (size_t)P * N * 16;
    const float2 hv = __half22float2(h2[(size_t)i * 16 + fpair]);
    const float b0 = bias[P * 32 + fpair * 2];
    const float b1 = bias[P * 32 + fpair * 2 + 1];
    __half2* c2 = reinterpret_cast<__half2*>(cat);

#pragma unroll
    for (int g = 0; g < 3; ++g) {
        const int* rp = rowptr + g * (N + 1);
        const unsigned* cg = csr + (size_t)g * E;
        const int beg = __builtin_amdgcn_readfirstlane(rp[i]);
        const int end = __builtin_amdgcn_readfirstlane(rp[i + 1]);
        const float dg = dis[g * N + i];

        float ax0 = 0.f, ay0 = 0.f, ax1 = 0.f, ay1 = 0.f;
        int j = beg;
        for (; j + 8 <= end; j += 8) {
            unsigned u0 = cg[j + 0], u1 = cg[j + 1], u2 = cg[j + 2], u3 = cg[j + 3];
            unsigned u4 = cg[j + 4], u5 = cg[j + 5], u6 = cg[j + 6], u7 = cg[j + 7];
            unsigned ua = e1 ? (e0 ? u3 : u2) : (e0 ? u1 : u0);
            unsigned ub = e1 ? (e0 ? u7 : u6) : (e0 ? u5 : u4);
            float2 A = __half22float2(h2[(size_t)(ua & 0xFFFFu) * 16 + fpair]);
            float2 Bv = __half22float2(h2[(size_t)(ub & 0xFFFFu) * 16 + fpair]);
            float wa = __half2float(__ushort_as_half((unsigned short)(ua >> 16)));
            float wb = __half2float(__ushort_as_half((unsigned short)(ub >> 16)));
            ax0 = fmaf(wa, A.x, ax0);
            ay0 = fmaf(wa, A.y, ay0);
            ax1 = fmaf(wb, Bv.x, ax1);
            ay1 = fmaf(wb, Bv.y, ay1);
        }
        for (; j < end; j += 4) {        // masked quad tail (end is SGPR-uniform)
            const int jm = end - 1;
            unsigned u0 = cg[j];
            unsigned u1 = (j + 1 <= jm) ? cg[j + 1] : 0u;   // w bits 0 -> contributes 0
            unsigned u2 = (j + 2 <= jm) ? cg[j + 2] : 0u;
            unsigned u3 = (j + 3 <= jm) ? cg[j + 3] : 0u;
            unsigned ua = e1 ? (e0 ? u3 : u2) : (e0 ? u1 : u0);
            float2 A = __half22float2(h2[(size_t)(ua & 0xFFFFu) * 16 + fpair]);
            float wa = __half2float(__ushort_as_half((unsigned short)(ua >> 16)));
            ax0 = fmaf(wa, A.x, ax0);
            ay0 = fmaf(wa, A.y, ay0);
        }

        float sx = ax0 + ax1;
        float sy = ay0 + ay1;
        sx += __shfl_xor(sx, 16);
        sy += __shfl_xor(sy, 16);
        sx += __shfl_xor(sx, 32);
        sy += __shfl_xor(sy, 32);
        if (lane < 16) {
            float r0 = fmaf(dg, sx, dg * dg * hv.x) + b0;
            float r1 = fmaf(dg, sy, dg * dg * hv.y) + b1;
            r0 = r0 > 0.f ? r0 : 0.f;
            r1 = r1 > 0.f ? r1 : 0.f;
            c2[(size_t)i * 96 + g * 32 + P * 16 + fpair] = __floats2half2_rn(r0, r1);
        }
    }
}

// ============ head: pointwise conv (16 out) + log_softmax (fp16 cat) ============

__global__ __launch_bounds__(256) void k_final(const __half* __restrict__ cat,
                                               const float* __restrict__ convw,  // [16][192]
                                               const float* __restrict__ convb,  // [16]
                                               float* __restrict__ out, int n) {
    __shared__ float wl[16 * 196];
    __shared__ float bl[16];
    const int tid = threadIdx.x;
    for (int t = tid; t < 16 * 192; t += 256) {
        int o = t / 192;
        int k = t - o * 192;
        wl[o * 196 + k] = convw[t];
    }
    if (tid < 16) bl[tid] = convb[tid];
    __syncthreads();

    const int o = tid & 15;
    const int node = blockIdx.x * 16 + (tid >> 4);
    const int nc = node < n ? node : n - 1;

    const float4* xr4 = reinterpret_cast<const float4*>(cat + (size_t)nc * CATDIM);
    const float* wr = &wl[o * 196];
    float acc = bl[o];
#pragma unroll
    for (int k8 = 0; k8 < CATDIM / 8; ++k8) {
        float4 raw = xr4[k8];
        const __half2* hp = reinterpret_cast<const __half2*>(&raw);
        float2 f0 = __half22float2(hp[0]);
        float2 f1 = __half22float2(hp[1]);
        float2 f2 = __half22float2(hp[2]);
        float2 f3 = __half22float2(hp[3]);
        const float* w8 = wr + k8 * 8;
        acc += f0.x * w8[0] + f0.y * w8[1] + f1.x * w8[2] + f1.y * w8[3] +
               f2.x * w8[4] + f2.y * w8[5] + f3.x * w8[6] + f3.y * w8[7];
    }

    float m = acc;
    m = fmaxf(m, __shfl_xor(m, 1));
    m = fmaxf(m, __shfl_xor(m, 2));
    m = fmaxf(m, __shfl_xor(m, 4));
    m = fmaxf(m, __shfl_xor(m, 8));
    float s = __expf(acc - m);
    s += __shfl_xor(s, 1);
    s += __shfl_xor(s, 2);
    s += __shfl_xor(s, 4);
    s += __shfl_xor(s, 8);
    if (node < n) out[(size_t)node * 16 + o] = acc - m - logf(s);
}

// ============ launch ============

extern "C" void kernel_launch(void* const* d_in, const int* in_sizes, int n_in,
                              void* d_out, int out_size, void* d_ws, size_t ws_size,
                              hipStream_t stream) {
    const float* x      = (const float*)d_in[0];
    const int*   ei     = (const int*)d_in[1];
    const int*   e_in   = (const int*)d_in[2];
    const int*   e_out  = (const int*)d_in[3];
    const float* in_w   = (const float*)d_in[4];
    const float* out_w  = (const float*)d_in[5];
    const float* lin1_w = (const float*)d_in[6];
    const float* lin2_w = (const float*)d_in[7];
    const float* bias1  = (const float*)d_in[8];
    const float* bias2  = (const float*)d_in[9];
    const float* conv_w = (const float*)d_in[10];
    const float* conv_b = (const float*)d_in[11];
    float* out = (float*)d_out;

    const int N = in_sizes[0] / 128;
    const int E = in_sizes[1] / 2;
    const int NB = (N + 63) >> 6;              // dest buckets of 64 nodes
    const int nchunks = (E + CH - 1) / CH;
    const int L = NB * nchunks;
    const int nblkS = (L + SCTILE - 1) / SCTILE;   // <=256 for this problem size

    // workspace layout (4B units; wider types kept 8B/16B aligned)
    float* ws = (float*)d_ws;
    size_t o = 0;
    float* dis    = ws + o;            o += (size_t)3 * N;
    int*   rowptr = (int*)(ws + o);    o += ((size_t)3 * (N + 1) + 1) & ~1ull;
    int*   bbase  = (int*)(ws + o);    o += ((size_t)3 * (NB + 1) + 1) & ~1ull;
    int*   bsum   = (int*)(ws + o);    o += ((size_t)3 * nblkS + 1) & ~1ull;
    int*   bh     = (int*)(ws + o);    o += ((size_t)3 * L + 3) & ~3ull;   // bucket-major
    __half* h     = (__half*)(ws + o); o += (size_t)N * (FDIM / 2);        // fp16, [2][N][32]
    o = (o + 3) & ~3ull;
    unsigned* csr = (unsigned*)(ws + o); o += (size_t)3 * E;               // 4B packed
    o = (o + 3) & ~3ull;
    __half* cat   = (__half*)(ws + o); o += (size_t)N * (CATDIM / 2);      // fp16
    int2*  barr   = (int2*)cat;        // alias: bucket array dead before cat written

    const int B = 256;

    // CSR build: deterministic two-pass binning (no global atomics)
    hipLaunchKernelGGL(k_chist, dim3(nchunks, 3), dim3(B), 0, stream, ei, e_in, e_out, bh, NB, nchunks, E);
    hipLaunchKernelGGL(k_scan_a, dim3(nblkS, 3), dim3(B), 0, stream, bh, bsum, L, nblkS);
    hipLaunchKernelGGL(k_scan_b, dim3(3), dim3(B), 0, stream, bsum, nblkS);
    hipLaunchKernelGGL(k_scan_c, dim3(nblkS, 3), dim3(B), 0, stream, bh, bsum, bbase, L, nblkS, NB, nchunks, E);
    hipLaunchKernelGGL(k_cfill, dim3(nchunks, 3), dim3(B), 0, stream,
                       ei, e_in, e_out, in_w, out_w, bh, barr, NB, nchunks, E);
    hipLaunchKernelGGL(k_deg, dim3(NB, 3), dim3(B), 0, stream, barr, bbase, rowptr, dis, N, E, NB);
    hipLaunchKernelGGL(k_place, dim3(NB, 3), dim3(B), 0, stream, barr, bbase, rowptr, dis, csr, N, E, NB);

    // layer 1
    hipLaunchKernelGGL((k_gemm<128, 64, float>), dim3((N + 63) / 64), dim3(B), 0, stream, x, lin1_w, h, N);
    hipLaunchKernelGGL((k_gather<0>), dim3((N + 3) / 4), dim3(B), 0, stream,
                       h, dis, rowptr, csr, bias1, cat, N, E);
    hipLaunchKernelGGL((k_gather<1>), dim3((N + 3) / 4), dim3(B), 0, stream,
                       h, dis, rowptr, csr, bias1, cat, N, E);

    // layer 2
    hipLaunchKernelGGL((k_gemm<192, 96, __half>), dim3((N + 63) / 64), dim3(B), 0, stream, cat, lin2_w, h, N);
    hipLaunchKernelGGL((k_gather<0>), dim3((N + 3) / 4), dim3(B), 0, stream,
                       h, dis, rowptr, csr, bias2, cat, N, E);
    hipLaunchKernelGGL((k_gather<1>), dim3((N + 3) / 4), dim3(B), 0, stream,
                       h, dis, rowptr, csr, bias2, cat, N, E);

    // head
    hipLaunchKernelGGL(k_final, dim3((N + 15) / 16), dim3(B), 0, stream, cat, conv_w, conv_b, out, N);
}